// Round 1
// 270.667 us; speedup vs baseline: 1.0060x; 1.0060x over previous
//
#include <hip/hip_runtime.h>

// Problem constants (fixed by the reference):
//   img [8192,1024] f32, txt [8192,1024] f32, both l2-normalized
//   set sizes si=st=4, t=16, tts=1, DENOM=2  -> out[bi][bt] = (right+left)/128
#define N_ROWS 8192
#define DIM    1024
#define BOUT   2048
#define BM 256
#define BN 256
#define BK 64
#define KTILES (DIM / BK)   // 16

typedef unsigned short u16;
typedef __attribute__((ext_vector_type(4))) unsigned short u16x4;
typedef __attribute__((ext_vector_type(8))) short short8;   // 8 bf16 MFMA A/B frag
typedef __attribute__((ext_vector_type(4))) float f32x4;    // MFMA C/D frag

// fp32 -> bf16 round-to-nearest-even
__device__ __forceinline__ u16 f2bf(float f) {
  unsigned u = __float_as_uint(f);
  u += 0x7fffu + ((u >> 16) & 1u);
  return (u16)(u >> 16);
}

__global__ void cast_kernel(const float* __restrict__ a, const float* __restrict__ b,
                            u16* __restrict__ oa, u16* __restrict__ ob) {
  const size_t i = ((size_t)blockIdx.x * 256 + threadIdx.x) * 4;
  float4 va = *reinterpret_cast<const float4*>(a + i);
  float4 vb = *reinterpret_cast<const float4*>(b + i);
  u16x4 ua, ub;
  ua[0] = f2bf(va.x); ua[1] = f2bf(va.y); ua[2] = f2bf(va.z); ua[3] = f2bf(va.w);
  ub[0] = f2bf(vb.x); ub[1] = f2bf(vb.y); ub[2] = f2bf(vb.z); ub[3] = f2bf(vb.w);
  *reinterpret_cast<u16x4*>(oa + i) = ua;
  *reinterpret_cast<u16x4*>(ob + i) = ub;
}

// async 16B global->LDS copy (wave-uniform LDS base + lane*16)
__device__ __forceinline__ void async_cp16(const u16* g, u16* l) {
  __builtin_amdgcn_global_load_lds(
      (const __attribute__((address_space(1))) void*)g,
      (__attribute__((address_space(3))) void*)l, 16, 0, 0);
}

// 256x256 8-phase GEMM (NT: A[M,K], B[N,K] row-major, dist = A.B^T) with fused
// smooth-chamfer epilogue. Template: learn_hip m201 (T1+T2+T3+T4+T5).
// 8 waves (2Mx4N), per-wave C = 128x64. LDS = 2 buffers x (A 256x64 + B 256x64)
// bf16 = 128 KiB (dynamic). st_16x32 swizzle: byte ^= ((row>>2)&1)<<5, applied
// as inverse-swizzled GLOBAL source (linear global_load_lds dest) + swizzled
// ds_read address (rule #21: both-sides-or-neither).
__global__ __launch_bounds__(512, 2) void gemm_chamfer(
    const u16* __restrict__ A, const u16* __restrict__ B, float* __restrict__ out) {
  extern __shared__ __align__(16) u16 sm[];   // 131072 B

  const int tid  = threadIdx.x;
  const int lane = tid & 63;
  const int wave = tid >> 6;
  const int wm = wave >> 2;       // 0..1  (row half of block tile)
  const int wn = wave & 3;        // 0..3  (col quarter)
  const int lm = lane & 15;
  const int lq = lane >> 4;

  // XCD-aware bijective swizzle: nwg=1024, 8 XCDs -> 128 consecutive tiles/XCD
  // (4 block-rows/XCD share A panels in that XCD's L2)
  const int bid = (int)blockIdx.x;
  const int swz = (bid & 7) * 128 + (bid >> 3);
  const int bm0 = (swz >> 5) * BM;
  const int bn0 = (swz & 31) * BN;

  // ---- staging map: thread t -> row (t>>3) within a 64-row chunk, 16B k-chunk
  // (t&7). LDS dest is LINEAR row-major (base + t*16B). Source k-offset is
  // pre-XOR'd so that LDS[swz(d)] = logical data (involution).
  const int sr8 = tid >> 3;
  const int kx  = ((tid & 7) * 8) ^ (((sr8 >> 2) & 1) * 16);   // swizzled src col (elems)
  const u16* aG = A + (size_t)(bm0 + sr8) * DIM + kx;
  const u16* bG = B + (size_t)(bn0 + sr8) * DIM + kx;
  const int ldst = tid * 8;       // u16 offset within a 64-row (8192 u16) region

  // stage one 128-row half-tile (h) of k-tile X: 2 x global_load_lds per thread
#define STAGE(gbase, lbuf, X, h)                                              \
  do {                                                                        \
    const u16* _g = (gbase) + ((h) ? (size_t)128 * DIM : 0) + (size_t)(X) * BK; \
    u16* _l = (lbuf) + (h) * 8192 + ldst;                                     \
    async_cp16(_g, _l);                                                       \
    async_cp16(_g + (size_t)64 * DIM, _l + 4096);                             \
  } while (0)

  // ---- fragment-read constants. row = .. + lm; swizzle bit = (row>>2)&1 = (lm>>2)&1
  const int fswz = ((lm >> 2) & 1) << 4;        // u16 units (= 32B byte-XOR)
  const int ck0 = (lq * 8) ^ fswz;              // k-subtile 0 col offset
  const int ck1 = (32 + lq * 8) ^ fswz;         // k-subtile 1 col offset
  const int aR = (wm * 128 + lm) * 64;          // per-lane A row base (u16)
  const int bR = (wn * 64 + lm) * 64;           // per-lane B row base (u16)

  f32x4 acc[8][4] = {};       // 128 VGPR accumulator: [MT 0..7][NT 0..3]
  short8 af[2][4];            // current A-half frags [ks][mt]
  short8 bfr[2][2][2];        // both B-half frags    [bh][ks][nt]

  u16* const buf0A = sm;
  u16* const buf0B = sm + 16384;
  u16* const buf1A = sm + 32768;
  u16* const buf1B = sm + 49152;

  // ---- prologue: tile0 complete (8 loads) + tile1 B0,B1,A0 (6 loads);
  // A1(tile1) is issued at u=0.P1 (steady-state pattern). vmcnt(6) -> tile0 landed.
  STAGE(aG, buf0A, 0, 0); STAGE(aG, buf0A, 0, 1);
  STAGE(bG, buf0B, 0, 0); STAGE(bG, buf0B, 0, 1);
  STAGE(bG, buf1B, 1, 0); STAGE(bG, buf1B, 1, 1);
  STAGE(aG, buf1A, 1, 0);
  asm volatile("s_waitcnt vmcnt(6)" ::: "memory");
  __builtin_amdgcn_s_barrier();

#define LOAD_A(bufA, ah)                                                      \
  _Pragma("unroll")                                                           \
  for (int mt = 0; mt < 4; ++mt) {                                            \
    af[0][mt] = *reinterpret_cast<const short8*>((bufA) + aR + ((ah) * 64 + mt * 16) * 64 + ck0); \
    af[1][mt] = *reinterpret_cast<const short8*>((bufA) + aR + ((ah) * 64 + mt * 16) * 64 + ck1); \
  }

#define LOAD_B(bufB, bh)                                                      \
  _Pragma("unroll")                                                           \
  for (int nt = 0; nt < 2; ++nt) {                                            \
    bfr[bh][0][nt] = *reinterpret_cast<const short8*>((bufB) + bR + ((bh) * 32 + nt * 16) * 64 + ck0); \
    bfr[bh][1][nt] = *reinterpret_cast<const short8*>((bufB) + bR + ((bh) * 32 + nt * 16) * 64 + ck1); \
  }

#define MFMA_Q(ah, bh)                                                        \
  _Pragma("unroll")                                                           \
  for (int mt = 0; mt < 4; ++mt)                                              \
    _Pragma("unroll")                                                         \
    for (int nt = 0; nt < 2; ++nt) {                                          \
      acc[(ah)*4+mt][(bh)*2+nt] = __builtin_amdgcn_mfma_f32_16x16x32_bf16(af[0][mt], bfr[bh][0][nt], acc[(ah)*4+mt][(bh)*2+nt], 0, 0, 0); \
      acc[(ah)*4+mt][(bh)*2+nt] = __builtin_amdgcn_mfma_f32_16x16x32_bf16(af[1][mt], bfr[bh][1][nt], acc[(ah)*4+mt][(bh)*2+nt], 0, 0, 0); \
    }

  // barrier + drain LDS reads + pin MFMA cluster after the wait (rule #18)
#define BAR1_WAIT()                                                           \
  __builtin_amdgcn_s_barrier();                                               \
  asm volatile("s_waitcnt lgkmcnt(0)" ::: "memory");                          \
  __builtin_amdgcn_sched_barrier(0)

  // K-loop: 4 phases/K-tile, quadrant order (A0B0)(A0B1)(A1B1)(A1B0).
  // LDS liveness: B halves of cur buffer dead after P2, A halves after P3.
  // Counted vmcnt(6) at boundaries keeps 3 half-tiles (6 loads) in flight.
#pragma unroll 2
  for (int u = 0; u < KTILES; ++u) {
    u16* const curA = sm + (u & 1) * 32768;
    u16* const curB = curA + 16384;
    u16* const nxtA = sm + ((u & 1) ^ 1) * 32768;

    // ---- P1: read Ah0(8) + Bh0(4); stage A1(u+1) -> other buffer (dead tile u-1)
    LOAD_A(curA, 0);
    LOAD_B(curB, 0);
    if (u + 1 < KTILES) STAGE(aG, nxtA, u + 1, 1);
    BAR1_WAIT();
    __builtin_amdgcn_s_setprio(1);
    MFMA_Q(0, 0);
    __builtin_amdgcn_s_setprio(0);
    __builtin_amdgcn_s_barrier();

    // ---- P2: read Bh1(4)
    LOAD_B(curB, 1);
    BAR1_WAIT();
    __builtin_amdgcn_s_setprio(1);
    MFMA_Q(0, 1);
    __builtin_amdgcn_s_setprio(0);
    __builtin_amdgcn_s_barrier();

    // ---- P3: read Ah1(8); stage B0(u+2) -> cur buffer (B reads done at P2)
    LOAD_A(curA, 1);
    if (u + 2 < KTILES) STAGE(bG, curB, u + 2, 0);
    BAR1_WAIT();
    __builtin_amdgcn_s_setprio(1);
    MFMA_Q(1, 1);
    __builtin_amdgcn_s_setprio(0);
    __builtin_amdgcn_s_barrier();

    // ---- P4: regs only; stage B1(u+2), A0(u+2) (A reads done at P3)
    if (u + 2 < KTILES) { STAGE(bG, curB, u + 2, 1); STAGE(aG, curA, u + 2, 0); }
    __builtin_amdgcn_s_barrier();
    __builtin_amdgcn_s_setprio(1);
    MFMA_Q(1, 0);    // Bh0 still live in regs from P1
    __builtin_amdgcn_s_setprio(0);
    // boundary: next tile fully landed, 3 half-tiles (6 loads) stay in flight
    if (u < KTILES - 2) asm volatile("s_waitcnt vmcnt(6)" ::: "memory");
    else                asm volatile("s_waitcnt vmcnt(0)" ::: "memory");
    __builtin_amdgcn_s_barrier();
  }

  // ---- fused chamfer epilogue (identical math/order to verified 128² kernel).
  // C layout: col = lane&15, row = lq*4 + reg; set blocks 4-aligned both dims.
#pragma unroll
  for (int MT = 0; MT < 8; ++MT) {
#pragma unroll
    for (int NT = 0; NT < 4; ++NT) {
      f32x4 c = acc[MT][NT];
      float e0 = __expf(16.0f * c[0]);
      float e1 = __expf(16.0f * c[1]);
      float e2 = __expf(16.0f * c[2]);
      float e3 = __expf(16.0f * c[3]);
      // left partial: log of sum over the 4 img-set rows (in-lane), per column
      float l = __logf(e0 + e1 + e2 + e3);
      // right: per-row sums over the 4 txt-set columns (cross-lane)
      e0 += __shfl_xor(e0, 1); e0 += __shfl_xor(e0, 2);
      e1 += __shfl_xor(e1, 1); e1 += __shfl_xor(e1, 2);
      e2 += __shfl_xor(e2, 1); e2 += __shfl_xor(e2, 2);
      e3 += __shfl_xor(e3, 1); e3 += __shfl_xor(e3, 2);
      float r = __logf(e0) + __logf(e1) + __logf(e2) + __logf(e3);
      // left: sum the per-column logs over the 4 txt-set columns
      l += __shfl_xor(l, 1); l += __shfl_xor(l, 2);
      if ((lane & 3) == 0) {
        const int obi = ((bm0 + wm * 128 + MT * 16) >> 2) + lq;
        const int obt = ((bn0 + wn * 64 + NT * 16) >> 2) + (lm >> 2);
        out[(size_t)obi * BOUT + obt] = (r + l) * 0.0078125f;  // /128
      }
    }
  }
}

extern "C" void kernel_launch(void* const* d_in, const int* in_sizes, int n_in,
                              void* d_out, int out_size, void* d_ws, size_t ws_size,
                              hipStream_t stream) {
  const float* img = (const float*)d_in[0];
  const float* txt = (const float*)d_in[1];
  float* out = (float*)d_out;
  u16* bA = (u16*)d_ws;                       // 16 MiB
  u16* bB = bA + (size_t)N_ROWS * DIM;        // 16 MiB

  const int nPer = N_ROWS * DIM;              // 8388608 per input
  cast_kernel<<<dim3(nPer / (256 * 4)), dim3(256), 0, stream>>>(img, txt, bA, bB);

  // 128 KiB dynamic LDS needs the opt-in (host-side attribute set; not a
  // stream op, so graph-capture safe). Once per process.
  static bool attr_set = false;
  if (!attr_set) {
    hipFuncSetAttribute((const void*)gemm_chamfer,
                        hipFuncAttributeMaxDynamicSharedMemorySize, 131072);
    attr_set = true;
  }
  dim3 ggrid(N_ROWS / BM * (N_ROWS / BN));    // 1024 blocks (32x32 tiles)
  gemm_chamfer<<<ggrid, dim3(512), 131072, stream>>>(bA, bB, out);
}

// Round 2
// 255.895 us; speedup vs baseline: 1.0641x; 1.0577x over previous
//
#include <hip/hip_runtime.h>

// Problem constants (fixed by the reference):
//   img [8192,1024] f32, txt [8192,1024] f32, both l2-normalized
//   set sizes si=st=4, t=16, tts=1, DENOM=2  -> out[bi][bt] = (right+left)/128
#define N_ROWS 8192
#define DIM    1024
#define BOUT   2048
#define BM 256
#define BN 256
#define BK 64
#define KTILES (DIM / BK)   // 16

typedef unsigned short u16;
typedef __attribute__((ext_vector_type(4))) unsigned short u16x4;
typedef __attribute__((ext_vector_type(8))) short short8;   // 8 bf16 MFMA A/B frag
typedef __attribute__((ext_vector_type(4))) float f32x4;    // MFMA C/D frag

// fp32 -> bf16 round-to-nearest-even
__device__ __forceinline__ u16 f2bf(float f) {
  unsigned u = __float_as_uint(f);
  u += 0x7fffu + ((u >> 16) & 1u);
  return (u16)(u >> 16);
}

__global__ void cast_kernel(const float* __restrict__ a, const float* __restrict__ b,
                            u16* __restrict__ oa, u16* __restrict__ ob) {
  const size_t i = ((size_t)blockIdx.x * 256 + threadIdx.x) * 4;
  float4 va = *reinterpret_cast<const float4*>(a + i);
  float4 vb = *reinterpret_cast<const float4*>(b + i);
  u16x4 ua, ub;
  ua[0] = f2bf(va.x); ua[1] = f2bf(va.y); ua[2] = f2bf(va.z); ua[3] = f2bf(va.w);
  ub[0] = f2bf(vb.x); ub[1] = f2bf(vb.y); ub[2] = f2bf(vb.z); ub[3] = f2bf(vb.w);
  *reinterpret_cast<u16x4*>(oa + i) = ua;
  *reinterpret_cast<u16x4*>(ob + i) = ub;
}

// async 16B global->LDS copy (wave-uniform LDS base + lane*16)
__device__ __forceinline__ void async_cp16(const u16* g, u16* l) {
  __builtin_amdgcn_global_load_lds(
      (const __attribute__((address_space(1))) void*)g,
      (__attribute__((address_space(3))) void*)l, 16, 0, 0);
}

// 256x256 8-phase GEMM (NT: A[M,K], B[N,K] row-major, dist = A.B^T) with fused
// smooth-chamfer epilogue. Template: learn_hip m201 (T1+T2+T3+T4+T5).
// 8 waves (2Mx4N), per-wave C = 128x64. LDS = 2 buffers x (A 256x64 + B 256x64)
// bf16 = 128 KiB (dynamic).
//
// LDS swizzle (G4 full form, fixed in round 2): within each 64-row region,
// logical (row, col-chunk c of 8 u16) lives at LDS[row][c ^ (row&7)], i.e.
// byte ^= (row&7)<<4. Frag reads have row ≡ lm (mod 8), so slot = lq ^ (lm&7)
// spreads the 64 lanes 8-per-16B-slot with 8 distinct rows each -> conflict-
// free (8-cycle min per ds_read_b128). Applied BOTH sides (rule #21): inverse-
// swizzled GLOBAL source column (LDS dest stays linear for global_load_lds)
// + swizzled ds_read column. Round-1's 1-bit variant left 16-way conflicts
// (1.26e7 counter = ~64 cy/read) and capped MfmaUtil at 24%.
__global__ __launch_bounds__(512, 2) void gemm_chamfer(
    const u16* __restrict__ A, const u16* __restrict__ B, float* __restrict__ out) {
  extern __shared__ __align__(16) u16 sm[];   // 131072 B

  const int tid  = threadIdx.x;
  const int lane = tid & 63;
  const int wave = tid >> 6;
  const int wm = wave >> 2;       // 0..1  (row half of block tile)
  const int wn = wave & 3;        // 0..3  (col quarter)
  const int lm = lane & 15;
  const int lq = lane >> 4;

  // XCD-aware bijective swizzle: nwg=1024, 8 XCDs -> 128 consecutive tiles/XCD
  const int bid = (int)blockIdx.x;
  const int swz = (bid & 7) * 128 + (bid >> 3);
  const int bm0 = (swz >> 5) * BM;
  const int bn0 = (swz & 31) * BN;

  // ---- staging map: thread t -> row (t>>3) within a 64-row chunk, 16B chunk
  // (t&7). LDS dest is LINEAR row-major (base + t*16B). Source col-chunk is
  // pre-XOR'd by (row&7) so LDS[row][c] = global[row][c ^ (row&7)] (involution).
  const int sr8 = tid >> 3;
  const int kx  = (((tid & 7) ^ (sr8 & 7)) * 8);     // swizzled src col (u16)
  const u16* aG = A + (size_t)(bm0 + sr8) * DIM + kx;
  const u16* bG = B + (size_t)(bn0 + sr8) * DIM + kx;
  const int ldst = tid * 8;       // u16 offset within a 64-row (4096 u16) region

  // stage one 128-row half-tile (h) of k-tile X: 2 x global_load_lds per thread
#define STAGE(gbase, lbuf, X, h)                                              \
  do {                                                                        \
    const u16* _g = (gbase) + ((h) ? (size_t)128 * DIM : 0) + (size_t)(X) * BK; \
    u16* _l = (lbuf) + (h) * 8192 + ldst;                                     \
    async_cp16(_g, _l);                                                       \
    async_cp16(_g + (size_t)64 * DIM, _l + 4096);                             \
  } while (0)

  // ---- fragment-read constants. All frag rows ≡ lm (mod 8) -> XOR (lm&7)*8.
  const int fswz = (lm & 7) * 8;                // u16 units (= (row&7)<<4 bytes)
  const int ck0 = (lq * 8) ^ fswz;              // k-subtile 0 col offset
  const int ck1 = (32 + lq * 8) ^ fswz;         // k-subtile 1 col offset
  const int aR = (wm * 128 + lm) * 64;          // per-lane A row base (u16)
  const int bR = (wn * 64 + lm) * 64;           // per-lane B row base (u16)

  f32x4 acc[8][4] = {};       // 128 VGPR accumulator: [MT 0..7][NT 0..3]
  short8 af[2][4];            // current A-half frags [ks][mt]
  short8 bfr[2][2][2];        // both B-half frags    [bh][ks][nt]

  u16* const buf0A = sm;
  u16* const buf0B = sm + 16384;
  u16* const buf1A = sm + 32768;
  u16* const buf1B = sm + 49152;

  // ---- prologue: tile0 complete (8 loads) + tile1 B0,B1,A0 (6 loads);
  // A1(tile1) is issued at u=0.P1 (steady-state pattern). vmcnt(6) -> tile0 landed.
  STAGE(aG, buf0A, 0, 0); STAGE(aG, buf0A, 0, 1);
  STAGE(bG, buf0B, 0, 0); STAGE(bG, buf0B, 0, 1);
  STAGE(bG, buf1B, 1, 0); STAGE(bG, buf1B, 1, 1);
  STAGE(aG, buf1A, 1, 0);
  asm volatile("s_waitcnt vmcnt(6)" ::: "memory");
  __builtin_amdgcn_s_barrier();

#define LOAD_A(bufA, ah)                                                      \
  _Pragma("unroll")                                                           \
  for (int mt = 0; mt < 4; ++mt) {                                            \
    af[0][mt] = *reinterpret_cast<const short8*>((bufA) + aR + ((ah) * 64 + mt * 16) * 64 + ck0); \
    af[1][mt] = *reinterpret_cast<const short8*>((bufA) + aR + ((ah) * 64 + mt * 16) * 64 + ck1); \
  }

#define LOAD_B(bufB, bh)                                                      \
  _Pragma("unroll")                                                           \
  for (int nt = 0; nt < 2; ++nt) {                                            \
    bfr[bh][0][nt] = *reinterpret_cast<const short8*>((bufB) + bR + ((bh) * 32 + nt * 16) * 64 + ck0); \
    bfr[bh][1][nt] = *reinterpret_cast<const short8*>((bufB) + bR + ((bh) * 32 + nt * 16) * 64 + ck1); \
  }

#define MFMA_Q(ah, bh)                                                        \
  _Pragma("unroll")                                                           \
  for (int mt = 0; mt < 4; ++mt)                                              \
    _Pragma("unroll")                                                         \
    for (int nt = 0; nt < 2; ++nt) {                                          \
      acc[(ah)*4+mt][(bh)*2+nt] = __builtin_amdgcn_mfma_f32_16x16x32_bf16(af[0][mt], bfr[bh][0][nt], acc[(ah)*4+mt][(bh)*2+nt], 0, 0, 0); \
      acc[(ah)*4+mt][(bh)*2+nt] = __builtin_amdgcn_mfma_f32_16x16x32_bf16(af[1][mt], bfr[bh][1][nt], acc[(ah)*4+mt][(bh)*2+nt], 0, 0, 0); \
    }

  // barrier + drain LDS reads + pin MFMA cluster after the wait (rule #18)
#define BAR1_WAIT()                                                           \
  __builtin_amdgcn_s_barrier();                                               \
  asm volatile("s_waitcnt lgkmcnt(0)" ::: "memory");                          \
  __builtin_amdgcn_sched_barrier(0)

  // K-loop: 4 phases/K-tile, quadrant order (A0B0)(A0B1)(A1B1)(A1B0).
  // LDS liveness: B halves of cur buffer dead after P2, A halves after P3.
  // Counted vmcnt(6) at boundaries keeps 3 half-tiles (6 loads) in flight.
#pragma unroll 2
  for (int u = 0; u < KTILES; ++u) {
    u16* const curA = sm + (u & 1) * 32768;
    u16* const curB = curA + 16384;
    u16* const nxtA = sm + ((u & 1) ^ 1) * 32768;

    // ---- P1: read Ah0(8) + Bh0(4); stage A1(u+1) -> other buffer (dead tile u-1)
    LOAD_A(curA, 0);
    LOAD_B(curB, 0);
    if (u + 1 < KTILES) STAGE(aG, nxtA, u + 1, 1);
    asm volatile("s_waitcnt lgkmcnt(8)" ::: "memory");   // pre-drain (12-read phase)
    BAR1_WAIT();
    __builtin_amdgcn_s_setprio(1);
    MFMA_Q(0, 0);
    __builtin_amdgcn_s_setprio(0);
    __builtin_amdgcn_s_barrier();

    // ---- P2: read Bh1(4)
    LOAD_B(curB, 1);
    BAR1_WAIT();
    __builtin_amdgcn_s_setprio(1);
    MFMA_Q(0, 1);
    __builtin_amdgcn_s_setprio(0);
    __builtin_amdgcn_s_barrier();

    // ---- P3: read Ah1(8); stage B0(u+2) -> cur buffer (B reads done at P2)
    LOAD_A(curA, 1);
    if (u + 2 < KTILES) STAGE(bG, curB, u + 2, 0);
    BAR1_WAIT();
    __builtin_amdgcn_s_setprio(1);
    MFMA_Q(1, 1);
    __builtin_amdgcn_s_setprio(0);
    __builtin_amdgcn_s_barrier();

    // ---- P4: regs only; stage B1(u+2), A0(u+2) (A reads done at P3)
    if (u + 2 < KTILES) { STAGE(bG, curB, u + 2, 1); STAGE(aG, curA, u + 2, 0); }
    __builtin_amdgcn_s_barrier();
    __builtin_amdgcn_s_setprio(1);
    MFMA_Q(1, 0);    // Bh0 still live in regs from P1
    __builtin_amdgcn_s_setprio(0);
    // boundary: next tile fully landed, 3 half-tiles (6 loads) stay in flight
    if (u < KTILES - 2) asm volatile("s_waitcnt vmcnt(6)" ::: "memory");
    else                asm volatile("s_waitcnt vmcnt(0)" ::: "memory");
    __builtin_amdgcn_s_barrier();
  }

  // ---- fused chamfer epilogue (identical math/order to verified 128² kernel).
  // C layout: col = lane&15, row = lq*4 + reg; set blocks 4-aligned both dims.
#pragma unroll
  for (int MT = 0; MT < 8; ++MT) {
#pragma unroll
    for (int NT = 0; NT < 4; ++NT) {
      f32x4 c = acc[MT][NT];
      float e0 = __expf(16.0f * c[0]);
      float e1 = __expf(16.0f * c[1]);
      float e2 = __expf(16.0f * c[2]);
      float e3 = __expf(16.0f * c[3]);
      // left partial: log of sum over the 4 img-set rows (in-lane), per column
      float l = __logf(e0 + e1 + e2 + e3);
      // right: per-row sums over the 4 txt-set columns (cross-lane)
      e0 += __shfl_xor(e0, 1); e0 += __shfl_xor(e0, 2);
      e1 += __shfl_xor(e1, 1); e1 += __shfl_xor(e1, 2);
      e2 += __shfl_xor(e2, 1); e2 += __shfl_xor(e2, 2);
      e3 += __shfl_xor(e3, 1); e3 += __shfl_xor(e3, 2);
      float r = __logf(e0) + __logf(e1) + __logf(e2) + __logf(e3);
      // left: sum the per-column logs over the 4 txt-set columns
      l += __shfl_xor(l, 1); l += __shfl_xor(l, 2);
      if ((lane & 3) == 0) {
        const int obi = ((bm0 + wm * 128 + MT * 16) >> 2) + lq;
        const int obt = ((bn0 + wn * 64 + NT * 16) >> 2) + (lm >> 2);
        out[(size_t)obi * BOUT + obt] = (r + l) * 0.0078125f;  // /128
      }
    }
  }
}

extern "C" void kernel_launch(void* const* d_in, const int* in_sizes, int n_in,
                              void* d_out, int out_size, void* d_ws, size_t ws_size,
                              hipStream_t stream) {
  const float* img = (const float*)d_in[0];
  const float* txt = (const float*)d_in[1];
  float* out = (float*)d_out;
  u16* bA = (u16*)d_ws;                       // 16 MiB
  u16* bB = bA + (size_t)N_ROWS * DIM;        // 16 MiB

  const int nPer = N_ROWS * DIM;              // 8388608 per input
  cast_kernel<<<dim3(nPer / (256 * 4)), dim3(256), 0, stream>>>(img, txt, bA, bB);

  // 128 KiB dynamic LDS needs the opt-in (host-side attribute set; not a
  // stream op, so graph-capture safe). Once per process.
  static bool attr_set = false;
  if (!attr_set) {
    hipFuncSetAttribute((const void*)gemm_chamfer,
                        hipFuncAttributeMaxDynamicSharedMemorySize, 131072);
    attr_set = true;
  }
  dim3 ggrid(N_ROWS / BM * (N_ROWS / BN));    // 1024 blocks (32x32 tiles)
  gemm_chamfer<<<ggrid, dim3(512), 131072, stream>>>(bA, bB, out);
}